// Round 11
// baseline (1207.916 us; speedup 1.0000x reference)
//
#include <hip/hip_runtime.h>
#include <stdint.h>

#define INFV 1e9f

// ---------------- ws layout (bytes) ----------------
#define SIM_OFF  0           // 1024x8192 f32 sim (never overwritten; zx fused into dpk)
#define A_OFF    33554432    // 1024x8192 u16 prefix-argmin table, tiled 16x128 (4KB tiles)
#define INVT_OFF 50331648    // 1024 f32
#define INVE_OFF 50335744    // 8192 f32
#define H1_OFF   50368512    // 4096 u32 (after scank2: reused as carryG[3][1024] u64, re-zeroed)
#define H2_OFF   50384896    // 4096 u32 (carryG tail)
#define H3_OFF   50401280    // 256 u32
#define SEL_OFF  50402304    // 16 u32: [0]=rank R, [1]=key prefix, [2]=dropline f32 bits

// ---------------- norms + arange ----------------
__global__ __launch_bounds__(256) void normk(const float* __restrict__ T, const float* __restrict__ E,
                                             float* __restrict__ invt, float* __restrict__ inve,
                                             float* __restrict__ out) {
  int row = blockIdx.x;
  const float* src = (row < 1024) ? (T + (size_t)row * 1024) : (E + (size_t)(row - 1024) * 1024);
  int tid = threadIdx.x;
  float4 v = ((const float4*)src)[tid];
  float s = v.x * v.x + v.y * v.y + v.z * v.z + v.w * v.w;
  #pragma unroll
  for (int d = 1; d < 64; d <<= 1) s += __shfl_xor(s, d);
  __shared__ float wsum[4];
  if ((tid & 63) == 0) wsum[tid >> 6] = s;
  __syncthreads();
  if (tid == 0) {
    float tot = wsum[0] + wsum[1] + wsum[2] + wsum[3];
    float inv = 1.0f / fmaxf(sqrtf(tot), 1e-12f);
    if (row < 1024) invt[row] = inv; else inve[row - 1024] = inv;
  }
  if (blockIdx.x < 4) {
    int i = blockIdx.x * 256 + tid;
    out[1024 + i] = (float)i;
  }
}

// ---------------- f32 GEMM: sim = (T . E^T) * invt * inve ----------------
#define AP 132
__global__ __launch_bounds__(256) void gemmk(const float* __restrict__ T, const float* __restrict__ E,
                                             const float* __restrict__ invt, const float* __restrict__ inve,
                                             float* __restrict__ sim) {
  __shared__ float As[16 * AP];
  __shared__ float Bs[16 * AP];
  int tid = threadIdx.x;
  int i0 = blockIdx.y * 128;
  int j0 = blockIdx.x * 128;
  int tx = tid & 15, ty = tid >> 4;
  float acc[8][8];
  #pragma unroll
  for (int a = 0; a < 8; a++)
    #pragma unroll
    for (int b = 0; b < 8; b++) acc[a][b] = 0.f;

  int q = tid * 2;
  int r = q >> 2;
  int s4 = (q & 3) * 4;
  const float* Ag = T + (size_t)(i0 + r) * 1024 + s4;
  const float* Bg = E + (size_t)(j0 + r) * 1024 + s4;

  for (int kb = 0; kb < 64; kb++) {
    float4 a0 = *(const float4*)(Ag + kb * 16);
    float4 a1 = *(const float4*)(Ag + kb * 16 + 4);
    float4 b0 = *(const float4*)(Bg + kb * 16);
    float4 b1 = *(const float4*)(Bg + kb * 16 + 4);
    __syncthreads();
    As[(s4 + 0) * AP + r] = a0.x; As[(s4 + 1) * AP + r] = a0.y;
    As[(s4 + 2) * AP + r] = a0.z; As[(s4 + 3) * AP + r] = a0.w;
    As[(s4 + 4) * AP + r] = a1.x; As[(s4 + 5) * AP + r] = a1.y;
    As[(s4 + 6) * AP + r] = a1.z; As[(s4 + 7) * AP + r] = a1.w;
    Bs[(s4 + 0) * AP + r] = b0.x; Bs[(s4 + 1) * AP + r] = b0.y;
    Bs[(s4 + 2) * AP + r] = b0.z; Bs[(s4 + 3) * AP + r] = b0.w;
    Bs[(s4 + 4) * AP + r] = b1.x; Bs[(s4 + 5) * AP + r] = b1.y;
    Bs[(s4 + 6) * AP + r] = b1.z; Bs[(s4 + 7) * AP + r] = b1.w;
    __syncthreads();
    #pragma unroll
    for (int k = 0; k < 16; k++) {
      float a[8], b[8];
      *(float4*)&a[0] = *(float4*)&As[k * AP + ty * 8];
      *(float4*)&a[4] = *(float4*)&As[k * AP + ty * 8 + 4];
      *(float4*)&b[0] = *(float4*)&Bs[k * AP + tx * 8];
      *(float4*)&b[4] = *(float4*)&Bs[k * AP + tx * 8 + 4];
      #pragma unroll
      for (int ii = 0; ii < 8; ii++)
        #pragma unroll
        for (int jj = 0; jj < 8; jj++) acc[ii][jj] += a[ii] * b[jj];
    }
  }
  float ie[8];
  #pragma unroll
  for (int jj = 0; jj < 8; jj++) ie[jj] = inve[j0 + tx * 8 + jj];
  #pragma unroll
  for (int ii = 0; ii < 8; ii++) {
    float itv = invt[i0 + ty * 8 + ii];
    float o[8];
    #pragma unroll
    for (int jj = 0; jj < 8; jj++) o[jj] = acc[ii][jj] * itv * ie[jj];
    float* dst = &sim[(size_t)(i0 + ty * 8 + ii) * 8192 + j0 + tx * 8];
    *(float4*)dst = *(float4*)&o[0];
    *(float4*)(dst + 4) = *(float4*)&o[4];
  }
}

// ---------------- exact k-th largest: 3-pass radix select ----------------
__device__ inline unsigned keyOf(float f) {
  unsigned u = __float_as_uint(f);
  return (u & 0x80000000u) ? ~u : (u | 0x80000000u);
}

__global__ __launch_bounds__(256) void histk(const float* __restrict__ sim, unsigned* __restrict__ hist,
                                             const unsigned* __restrict__ sel, int pass) {
  __shared__ unsigned lh[4096];
  int tid = threadIdx.x;
  int nb = (pass == 2) ? 256 : 4096;
  for (int b = tid; b < nb; b += 256) lh[b] = 0;
  __syncthreads();
  unsigned prefix = (pass == 0) ? 0u : sel[1];
  size_t base = (size_t)blockIdx.x * 4096 + tid * 4;
  #pragma unroll
  for (int it = 0; it < 4; it++) {
    float4 f = *(const float4*)(sim + base + it * 1024);
    float vals[4] = {f.x, f.y, f.z, f.w};
    #pragma unroll
    for (int e = 0; e < 4; e++) {
      unsigned u = keyOf(vals[e]);
      if (pass == 0) {
        atomicAdd(&lh[u >> 20], 1u);
      } else if (pass == 1) {
        if ((u >> 20) == (prefix >> 20)) atomicAdd(&lh[(u >> 8) & 0xFFFu], 1u);
      } else {
        if ((u >> 8) == (prefix >> 8)) atomicAdd(&lh[u & 0xFFu], 1u);
      }
    }
  }
  __syncthreads();
  for (int b = tid; b < nb; b += 256) if (lh[b]) atomicAdd(&hist[b], lh[b]);
}

__global__ __launch_bounds__(256) void scank(const unsigned* __restrict__ hist, unsigned* __restrict__ sel, int pass) {
  int tid = threadIdx.x;
  int nb = (pass == 2) ? 256 : 4096;
  int per = nb / 256;
  unsigned R = (pass == 0) ? 5872027u : sel[0];
  unsigned prefix = (pass == 0) ? 0u : sel[1];
  unsigned cnt[16];
  unsigned s = 0;
  for (int i = 0; i < per; i++) { cnt[i] = hist[tid * per + i]; s += cnt[i]; }
  unsigned incl = s;
  #pragma unroll
  for (int d = 1; d < 64; d <<= 1) { unsigned o = __shfl_up(incl, d); if ((tid & 63) >= d) incl += o; }
  __shared__ unsigned wt[4], wsc[4];
  if ((tid & 63) == 63) wt[tid >> 6] = incl;
  __syncthreads();
  if (tid < 4) {
    unsigned v = wt[tid];
    #pragma unroll
    for (int d = 1; d < 4; d <<= 1) { unsigned o = __shfl_up(v, d); if (tid >= d) v += o; }
    wsc[tid] = v;
  }
  __syncthreads();
  unsigned excl = incl - s + ((tid >> 6) ? wsc[(tid >> 6) - 1] : 0u);
  unsigned c = excl;
  for (int i = 0; i < per; i++) {
    unsigned nc = c + cnt[i];
    if (c < R && R <= nc) {
      unsigned bin = (unsigned)(tid * per + i);
      sel[0] = R - c;
      unsigned np_;
      if (pass == 0) np_ = bin << 20;
      else if (pass == 1) np_ = prefix | (bin << 8);
      else np_ = prefix | bin;
      sel[1] = np_;
      if (pass == 2) {
        unsigned key = np_;
        unsigned u = (key & 0x80000000u) ? (key ^ 0x80000000u) : ~key;
        ((float*)sel)[2] = __uint_as_float(u);
      }
    }
    c = nc;
  }
}

// ---------------- DPP helpers ----------------
template<int CTRL, int RM>
__device__ __forceinline__ float dppf(float old, float src) {
  return __int_as_float(__builtin_amdgcn_update_dpp(__float_as_int(old), __float_as_int(src), CTRL, RM, 0xf, false));
}
template<int CTRL, int RM>
__device__ __forceinline__ int dppi(int old, int src) {
  return __builtin_amdgcn_update_dpp(old, src, CTRL, RM, 0xf, false);
}

// full-wave shift-down-by-1 of x (lane l gets lane l-1's x; lane 0 gets `fill`)
__device__ __forceinline__ float wave_shr1(float x, float fill, int lane) {
  float rs  = dppf<0x111, 0xf>(INFV, x);   // row_shr:1 (invalid at lanes 0,16,32,48)
  float r15 = dppf<0x142, 0xa>(INFV, x);   // row_bcast:15 -> lanes 16..31 get l15, 48..63 get l47
  float r31 = dppf<0x143, 0xc>(INFV, x);   // row_bcast:31 -> lanes 32..63 get l31
  float r = rs;
  if (lane == 16 || lane == 48) r = r15;
  if (lane == 32) r = r31;
  if (lane == 0) r = fill;
  return r;
}

// ---------------- Drop-DTW DP: 4-WG x 8-wave skewed pipeline, sleep-backoff spins ----------------
// B_zi[j] = prefix-min_j of tv[j] = (drop - sim[zi-1][j-1]) + B_{zi-1}[j-1]   (zx fused).
// A[zi-1][j-1] = latest prefix-argmin <= j (exact backtrack choice of the reference).
// Global wave W = wg*8+w owns cols [2048*wg + 256*w, +256) (4/thread).
// Chained carry C_W(zi): LDS within WG, agent-scope global across WG boundaries.
// Spin-miss path uses s_sleep(1) so waiting waves DON'T burn SIMD issue slots that
// the producer waves (co-resident on the same SIMDs) need -- the chain then runs at
// wave-0's own issue rate instead of the spin-throttled rate.
__global__ __launch_bounds__(512) void dpk(const float* __restrict__ sim,
                                           const unsigned* __restrict__ sel,
                                           unsigned long long* __restrict__ carryG,
                                           unsigned short* __restrict__ A, float* __restrict__ out) {
  int tid = threadIdx.x;
  int lane = tid & 63, w = tid >> 6;
  int wg = blockIdx.x;
  int W = wg * 8 + w;
  int col0 = wg * 2048 + tid * 4;                // first of this thread's 4 columns
  float drop = ((const float*)sel)[2];
  __shared__ unsigned long long carry[7][1024];
  for (int i = tid; i < 7 * 1024; i += 512) ((unsigned long long*)carry)[i] = 0ull;
  __syncthreads();

  float r[4];
  #pragma unroll
  for (int u = 0; u < 4; u++) r[u] = 0.f;        // B_0 = 0 everywhere
  float rlast = 0.f;
  float pbfill = 0.f;
  int jj[4];
  #pragma unroll
  for (int u = 0; u < 4; u++) jj[u] = col0 + 1 + u;

  const float* zrow = sim + col0;
  // A-store base (tiled 16x128)
  unsigned short* abase = A + (size_t)(col0 >> 7) * 2048 + (col0 & 127);

  float b0[4], b1[4], b2[4], b3[4];
  *(float4*)&b0[0] = *(const float4*)(zrow);
  *(float4*)&b1[0] = *(const float4*)(zrow + 8192);
  *(float4*)&b2[0] = *(const float4*)(zrow + 16384);
  *(float4*)&b3[0] = *(const float4*)(zrow + 24576);

  // prefetched carry for the upcoming row
  unsigned long long pend = 0ull;
  if (w > 0)       pend = __hip_atomic_load(&carry[w - 1][0], __ATOMIC_RELAXED, __HIP_MEMORY_SCOPE_WORKGROUP);
  else if (wg > 0) pend = __hip_atomic_load(&carryG[(wg - 1) * 1024 + 0], __ATOMIC_RELAXED, __HIP_MEMORY_SCOPE_AGENT);

  auto body = [&](float (&dc)[4], int zi0) {
    unsigned want = (unsigned)(zi0 + 1) << 14;

    float fill = (W == 0) ? ((zi0 == 0) ? 0.f : INFV) : pbfill;
    float pb0 = wave_shr1(rlast, fill, lane);
    // tv[u] = (drop - sim) + B_prev  : identical ops/order to reference zx + prev
    float tv[4];
    { float zx0 = drop - dc[0]; tv[0] = zx0 + pb0; }
    #pragma unroll
    for (int u = 1; u < 4; u++) { float zxu = drop - dc[u]; tv[u] = zxu + r[u - 1]; }
    // prefetch sim row zi0+4 into the freed buffer
    if (zi0 + 4 < 1024) {
      *(float4*)&dc[0] = *(const float4*)(zrow + (size_t)(zi0 + 4) * 8192);
    }
    // in-thread inclusive prefix-min + latest-tie argmin
    int li[4];
    r[0] = tv[0]; li[0] = jj[0];
    #pragma unroll
    for (int u = 1; u < 4; u++) {
      bool t = (tv[u] <= r[u - 1]);
      r[u] = t ? tv[u] : r[u - 1];
      li[u] = t ? jj[u] : li[u - 1];
    }
    // wave-inclusive (min, latest-argmin) scan of thread totals via DPP
    float v = r[3]; int ix = li[3];
    { float sv = dppf<0x111, 0xf>(INFV, v); int si = dppi<0x111, 0xf>(0, ix); if (sv < v) { v = sv; ix = si; } }
    { float sv = dppf<0x112, 0xf>(INFV, v); int si = dppi<0x112, 0xf>(0, ix); if (sv < v) { v = sv; ix = si; } }
    { float sv = dppf<0x114, 0xf>(INFV, v); int si = dppi<0x114, 0xf>(0, ix); if (sv < v) { v = sv; ix = si; } }
    { float sv = dppf<0x118, 0xf>(INFV, v); int si = dppi<0x118, 0xf>(0, ix); if (sv < v) { v = sv; ix = si; } }
    { float sv = dppf<0x142, 0xa>(INFV, v); int si = dppi<0x142, 0xa>(0, ix); if (sv < v) { v = sv; ix = si; } }
    { float sv = dppf<0x143, 0xc>(INFV, v); int si = dppi<0x143, 0xc>(0, ix); if (sv < v) { v = sv; ix = si; } }
    // exclusive within wave
    float exv = dppf<0x111, 0xf>(INFV, v); int exi = dppi<0x111, 0xf>(0, ix);
    float e15 = dppf<0x142, 0xa>(INFV, v); int i15 = dppi<0x142, 0xa>(0, ix);
    float e31 = dppf<0x143, 0xc>(INFV, v); int i31 = dppi<0x143, 0xc>(0, ix);
    if (lane == 16 || lane == 48) { exv = e15; exi = i15; }
    if (lane == 32) { exv = e31; exi = i31; }

    // receive carry C_{W-1}(zi0): prefetched reg if fresh; sleep-backoff spin otherwise
    float cv; int ci;
    if (W > 0) {
      unsigned long long d = pend;
      if ((((unsigned)d) & 0xFFFFC000u) != want) {
        int guard = 0;
        if (w > 0) {
          do {
            __builtin_amdgcn_s_sleep(1);
            d = __hip_atomic_load(&carry[w - 1][zi0], __ATOMIC_RELAXED, __HIP_MEMORY_SCOPE_WORKGROUP);
          } while ((((unsigned)d) & 0xFFFFC000u) != want && ++guard < (1 << 20));
        } else {
          do {
            __builtin_amdgcn_s_sleep(1);
            d = __hip_atomic_load(&carryG[(wg - 1) * 1024 + zi0], __ATOMIC_RELAXED, __HIP_MEMORY_SCOPE_AGENT);
          } while ((((unsigned)d) & 0xFFFFC000u) != want && ++guard < (1 << 20));
        }
      }
      cv = __uint_as_float((unsigned)(d >> 32));
      ci = (int)((unsigned)d & 0x3FFFu);
    } else {
      cv = INFV; ci = 0;
    }
    // prefetch next row's carry now (one full row of slack before use)
    if (zi0 + 1 < 1024) {
      if (w > 0)       pend = __hip_atomic_load(&carry[w - 1][zi0 + 1], __ATOMIC_RELAXED, __HIP_MEMORY_SCOPE_WORKGROUP);
      else if (wg > 0) pend = __hip_atomic_load(&carryG[(wg - 1) * 1024 + zi0 + 1], __ATOMIC_RELAXED, __HIP_MEMORY_SCOPE_AGENT);
    }
    // publish combined C_W(zi0) = combine(C_{W-1}, T_W); own cols later -> win ties
    if (lane == 63 && W < 31) {
      bool t = (v <= cv);
      float cov = t ? v : cv;
      int coi = t ? ix : ci;
      unsigned long long pd = ((unsigned long long)__float_as_uint(cov) << 32)
                            | (unsigned)(coi & 0x3FFF) | (unsigned long long)want;
      if (w < 7) __hip_atomic_store(&carry[w][zi0], pd, __ATOMIC_RELAXED, __HIP_MEMORY_SCOPE_WORKGROUP);
      else       __hip_atomic_store(&carryG[wg * 1024 + zi0], pd, __ATOMIC_RELAXED, __HIP_MEMORY_SCOPE_AGENT);
    }

    // init = combine(received carry, wave-exclusive); then PARALLEL per-column merge
    float pv; int pi;
    { bool t = (exv <= cv); pv = t ? exv : cv; pi = t ? exi : ci; }
    #pragma unroll
    for (int u = 0; u < 4; u++) {
      bool t = (r[u] <= pv);
      r[u] = t ? r[u] : pv;
      li[u] = t ? li[u] : pi;
    }
    rlast = r[3];
    pbfill = cv;

    unsigned pk0 = (unsigned)li[0] | ((unsigned)li[1] << 16);
    unsigned pk1 = (unsigned)li[2] | ((unsigned)li[3] << 16);
    *(uint2*)(abase + (size_t)(zi0 >> 4) * (64 * 2048) + ((zi0 & 15) << 7)) = make_uint2(pk0, pk1);
  };

  for (int zz = 0; zz < 1024; zz += 4) {
    body(b0, zz);
    body(b1, zz + 1);
    body(b2, zz + 2);
    body(b3, zz + 3);
  }
  if (wg == 3 && tid == 511) out[2048] = rlast;   // min(D0f[K,N], D1f[K,N])
}

// ---------------- backtrack (tiled A) ----------------
__global__ void btk(const unsigned short* __restrict__ A, float* __restrict__ out) {
  if (threadIdx.x != 0) return;
  int j = 8192;
  for (int zi = 1023; zi >= 0; zi--) {
    int col = j - 1;
    size_t idx = ((size_t)((zi >> 4) * 64 + (col >> 7))) * 2048 + ((zi & 15) << 7) + (col & 127);
    int p = A[idx];
    out[zi] = (float)(p - 1);
    j = p - 1;
  }
}

extern "C" void kernel_launch(void* const* d_in, const int* in_sizes, int n_in,
                              void* d_out, int out_size, void* d_ws, size_t ws_size,
                              hipStream_t stream) {
  (void)in_sizes; (void)n_in; (void)out_size; (void)ws_size;
  const float* T = (const float*)d_in[0];
  const float* E = (const float*)d_in[1];
  char* ws = (char*)d_ws;
  float* sim = (float*)(ws + SIM_OFF);
  unsigned short* A = (unsigned short*)(ws + A_OFF);
  float* invt = (float*)(ws + INVT_OFF);
  float* inve = (float*)(ws + INVE_OFF);
  unsigned* h1 = (unsigned*)(ws + H1_OFF);
  unsigned* h2 = (unsigned*)(ws + H2_OFF);
  unsigned* h3 = (unsigned*)(ws + H3_OFF);
  unsigned* sel = (unsigned*)(ws + SEL_OFF);
  unsigned long long* carryG = (unsigned long long*)(ws + H1_OFF);   // reused after radix select
  float* out = (float*)d_out;

  hipMemsetAsync(ws + H1_OFF, 0, 16384 + 16384 + 1024 + 64, stream);
  normk<<<9216, 256, 0, stream>>>(T, E, invt, inve, out);
  gemmk<<<dim3(64, 8), 256, 0, stream>>>(T, E, invt, inve, sim);
  histk<<<2048, 256, 0, stream>>>(sim, h1, sel, 0);
  scank<<<1, 256, 0, stream>>>(h1, sel, 0);
  histk<<<2048, 256, 0, stream>>>(sim, h2, sel, 1);
  scank<<<1, 256, 0, stream>>>(h2, sel, 1);
  histk<<<2048, 256, 0, stream>>>(sim, h3, sel, 2);
  scank<<<1, 256, 0, stream>>>(h3, sel, 2);
  hipMemsetAsync(ws + H1_OFF, 0, 3 * 1024 * 8, stream);   // zero carryG (h1/h2 now dead)
  dpk<<<4, 512, 0, stream>>>(sim, sel, carryG, A, out);
  btk<<<1, 64, 0, stream>>>(A, out);
}

// Round 12
// 1193.525 us; speedup vs baseline: 1.0121x; 1.0121x over previous
//
#include <hip/hip_runtime.h>
#include <stdint.h>

#define INFV 1e9f

// ---------------- ws layout (bytes) ----------------
#define SIM_OFF  0           // 1024x8192 f32 sim (never overwritten; zx fused into dpk)
#define A_OFF    33554432    // 1024x8192 u16 prefix-argmin table, tiled 16x128 (4KB tiles)
#define INVT_OFF 50331648    // 1024 f32 (dead after gemmk -> reused as carryG[7][1024] u64)
#define INVE_OFF 50335744    // 8192 f32 (dead after gemmk -> carryG tail)
#define H1_OFF   50368512    // 4096 u32 (dead after scank0 -> carryG tail)
#define H2_OFF   50384896    // 4096 u32 (partially carryG tail; dead after scank1)
#define H3_OFF   50401280    // 256 u32
#define SEL_OFF  50402304    // 16 u32: [0]=rank R, [1]=key prefix, [2]=dropline f32 bits

// ---------------- norms + arange ----------------
__global__ __launch_bounds__(256) void normk(const float* __restrict__ T, const float* __restrict__ E,
                                             float* __restrict__ invt, float* __restrict__ inve,
                                             float* __restrict__ out) {
  int row = blockIdx.x;
  const float* src = (row < 1024) ? (T + (size_t)row * 1024) : (E + (size_t)(row - 1024) * 1024);
  int tid = threadIdx.x;
  float4 v = ((const float4*)src)[tid];
  float s = v.x * v.x + v.y * v.y + v.z * v.z + v.w * v.w;
  #pragma unroll
  for (int d = 1; d < 64; d <<= 1) s += __shfl_xor(s, d);
  __shared__ float wsum[4];
  if ((tid & 63) == 0) wsum[tid >> 6] = s;
  __syncthreads();
  if (tid == 0) {
    float tot = wsum[0] + wsum[1] + wsum[2] + wsum[3];
    float inv = 1.0f / fmaxf(sqrtf(tot), 1e-12f);
    if (row < 1024) invt[row] = inv; else inve[row - 1024] = inv;
  }
  if (blockIdx.x < 4) {
    int i = blockIdx.x * 256 + tid;
    out[1024 + i] = (float)i;
  }
}

// ---------------- f32 GEMM: sim = (T . E^T) * invt * inve ----------------
#define AP 132
__global__ __launch_bounds__(256) void gemmk(const float* __restrict__ T, const float* __restrict__ E,
                                             const float* __restrict__ invt, const float* __restrict__ inve,
                                             float* __restrict__ sim) {
  __shared__ float As[16 * AP];
  __shared__ float Bs[16 * AP];
  int tid = threadIdx.x;
  int i0 = blockIdx.y * 128;
  int j0 = blockIdx.x * 128;
  int tx = tid & 15, ty = tid >> 4;
  float acc[8][8];
  #pragma unroll
  for (int a = 0; a < 8; a++)
    #pragma unroll
    for (int b = 0; b < 8; b++) acc[a][b] = 0.f;

  int q = tid * 2;
  int r = q >> 2;
  int s4 = (q & 3) * 4;
  const float* Ag = T + (size_t)(i0 + r) * 1024 + s4;
  const float* Bg = E + (size_t)(j0 + r) * 1024 + s4;

  for (int kb = 0; kb < 64; kb++) {
    float4 a0 = *(const float4*)(Ag + kb * 16);
    float4 a1 = *(const float4*)(Ag + kb * 16 + 4);
    float4 b0 = *(const float4*)(Bg + kb * 16);
    float4 b1 = *(const float4*)(Bg + kb * 16 + 4);
    __syncthreads();
    As[(s4 + 0) * AP + r] = a0.x; As[(s4 + 1) * AP + r] = a0.y;
    As[(s4 + 2) * AP + r] = a0.z; As[(s4 + 3) * AP + r] = a0.w;
    As[(s4 + 4) * AP + r] = a1.x; As[(s4 + 5) * AP + r] = a1.y;
    As[(s4 + 6) * AP + r] = a1.z; As[(s4 + 7) * AP + r] = a1.w;
    Bs[(s4 + 0) * AP + r] = b0.x; Bs[(s4 + 1) * AP + r] = b0.y;
    Bs[(s4 + 2) * AP + r] = b0.z; Bs[(s4 + 3) * AP + r] = b0.w;
    Bs[(s4 + 4) * AP + r] = b1.x; Bs[(s4 + 5) * AP + r] = b1.y;
    Bs[(s4 + 6) * AP + r] = b1.z; Bs[(s4 + 7) * AP + r] = b1.w;
    __syncthreads();
    #pragma unroll
    for (int k = 0; k < 16; k++) {
      float a[8], b[8];
      *(float4*)&a[0] = *(float4*)&As[k * AP + ty * 8];
      *(float4*)&a[4] = *(float4*)&As[k * AP + ty * 8 + 4];
      *(float4*)&b[0] = *(float4*)&Bs[k * AP + tx * 8];
      *(float4*)&b[4] = *(float4*)&Bs[k * AP + tx * 8 + 4];
      #pragma unroll
      for (int ii = 0; ii < 8; ii++)
        #pragma unroll
        for (int jj = 0; jj < 8; jj++) acc[ii][jj] += a[ii] * b[jj];
    }
  }
  float ie[8];
  #pragma unroll
  for (int jj = 0; jj < 8; jj++) ie[jj] = inve[j0 + tx * 8 + jj];
  #pragma unroll
  for (int ii = 0; ii < 8; ii++) {
    float itv = invt[i0 + ty * 8 + ii];
    float o[8];
    #pragma unroll
    for (int jj = 0; jj < 8; jj++) o[jj] = acc[ii][jj] * itv * ie[jj];
    float* dst = &sim[(size_t)(i0 + ty * 8 + ii) * 8192 + j0 + tx * 8];
    *(float4*)dst = *(float4*)&o[0];
    *(float4*)(dst + 4) = *(float4*)&o[4];
  }
}

// ---------------- exact k-th largest: 3-pass radix select ----------------
__device__ inline unsigned keyOf(float f) {
  unsigned u = __float_as_uint(f);
  return (u & 0x80000000u) ? ~u : (u | 0x80000000u);
}

__global__ __launch_bounds__(256) void histk(const float* __restrict__ sim, unsigned* __restrict__ hist,
                                             const unsigned* __restrict__ sel, int pass) {
  __shared__ unsigned lh[4096];
  int tid = threadIdx.x;
  int nb = (pass == 2) ? 256 : 4096;
  for (int b = tid; b < nb; b += 256) lh[b] = 0;
  __syncthreads();
  unsigned prefix = (pass == 0) ? 0u : sel[1];
  size_t base = (size_t)blockIdx.x * 4096 + tid * 4;
  #pragma unroll
  for (int it = 0; it < 4; it++) {
    float4 f = *(const float4*)(sim + base + it * 1024);
    float vals[4] = {f.x, f.y, f.z, f.w};
    #pragma unroll
    for (int e = 0; e < 4; e++) {
      unsigned u = keyOf(vals[e]);
      if (pass == 0) {
        atomicAdd(&lh[u >> 20], 1u);
      } else if (pass == 1) {
        if ((u >> 20) == (prefix >> 20)) atomicAdd(&lh[(u >> 8) & 0xFFFu], 1u);
      } else {
        if ((u >> 8) == (prefix >> 8)) atomicAdd(&lh[u & 0xFFu], 1u);
      }
    }
  }
  __syncthreads();
  for (int b = tid; b < nb; b += 256) if (lh[b]) atomicAdd(&hist[b], lh[b]);
}

__global__ __launch_bounds__(256) void scank(const unsigned* __restrict__ hist, unsigned* __restrict__ sel, int pass) {
  int tid = threadIdx.x;
  int nb = (pass == 2) ? 256 : 4096;
  int per = nb / 256;
  unsigned R = (pass == 0) ? 5872027u : sel[0];
  unsigned prefix = (pass == 0) ? 0u : sel[1];
  unsigned cnt[16];
  unsigned s = 0;
  for (int i = 0; i < per; i++) { cnt[i] = hist[tid * per + i]; s += cnt[i]; }
  unsigned incl = s;
  #pragma unroll
  for (int d = 1; d < 64; d <<= 1) { unsigned o = __shfl_up(incl, d); if ((tid & 63) >= d) incl += o; }
  __shared__ unsigned wt[4], wsc[4];
  if ((tid & 63) == 63) wt[tid >> 6] = incl;
  __syncthreads();
  if (tid < 4) {
    unsigned v = wt[tid];
    #pragma unroll
    for (int d = 1; d < 4; d <<= 1) { unsigned o = __shfl_up(v, d); if (tid >= d) v += o; }
    wsc[tid] = v;
  }
  __syncthreads();
  unsigned excl = incl - s + ((tid >> 6) ? wsc[(tid >> 6) - 1] : 0u);
  unsigned c = excl;
  for (int i = 0; i < per; i++) {
    unsigned nc = c + cnt[i];
    if (c < R && R <= nc) {
      unsigned bin = (unsigned)(tid * per + i);
      sel[0] = R - c;
      unsigned np_;
      if (pass == 0) np_ = bin << 20;
      else if (pass == 1) np_ = prefix | (bin << 8);
      else np_ = prefix | bin;
      sel[1] = np_;
      if (pass == 2) {
        unsigned key = np_;
        unsigned u = (key & 0x80000000u) ? (key ^ 0x80000000u) : ~key;
        ((float*)sel)[2] = __uint_as_float(u);
      }
    }
    c = nc;
  }
}

// ---------------- DPP helpers ----------------
template<int CTRL, int RM>
__device__ __forceinline__ float dppf(float old, float src) {
  return __int_as_float(__builtin_amdgcn_update_dpp(__float_as_int(old), __float_as_int(src), CTRL, RM, 0xf, false));
}
template<int CTRL, int RM>
__device__ __forceinline__ int dppi(int old, int src) {
  return __builtin_amdgcn_update_dpp(old, src, CTRL, RM, 0xf, false);
}

// full-wave shift-down-by-1 of x (lane l gets lane l-1's x; lane 0 gets `fill`)
__device__ __forceinline__ float wave_shr1(float x, float fill, int lane) {
  float rs  = dppf<0x111, 0xf>(INFV, x);   // row_shr:1 (invalid at lanes 0,16,32,48)
  float r15 = dppf<0x142, 0xa>(INFV, x);   // row_bcast:15 -> lanes 16..31 get l15, 48..63 get l47
  float r31 = dppf<0x143, 0xc>(INFV, x);   // row_bcast:31 -> lanes 32..63 get l31
  float r = rs;
  if (lane == 16 || lane == 48) r = r15;
  if (lane == 32) r = r31;
  if (lane == 0) r = fill;
  return r;
}

// ---------------- Drop-DTW DP: 8-WG x 4-wave (1 wave/SIMD) skewed pipeline ----------------
// B_zi[j] = prefix-min_j of tv[j] = (drop - sim[zi-1][j-1]) + B_{zi-1}[j-1]   (zx fused).
// A[zi-1][j-1] = latest prefix-argmin <= j (exact backtrack choice of the reference).
// Global wave W = wg*4+w owns cols [1024*wg + 256*w, +256) (4/thread). 32 waves on 32
// SIMDs (8 CUs) -- each wave owns its SIMD's full issue bandwidth.
// Chained carry C_W(zi): LDS within WG (3 boundaries, depth-1 prefetch: 120cy < P),
// agent-scope global across the 7 WG boundaries with DEPTH-4 register prefetch
// (slack 4P >= cross-XCD transport ~1500cy -- R10/R11's limiter). Write-once tagged
// u64 atoms, spin+sleep fallback; comparisons/tie rules verbatim -> bit-exact.
__global__ __launch_bounds__(256) void dpk(const float* __restrict__ sim,
                                           const unsigned* __restrict__ sel,
                                           unsigned long long* __restrict__ carryG,
                                           unsigned short* __restrict__ A, float* __restrict__ out) {
  int tid = threadIdx.x;
  int lane = tid & 63, w = tid >> 6;
  int wg = blockIdx.x;
  int W = wg * 4 + w;
  int col0 = wg * 1024 + tid * 4;                // first of this thread's 4 columns
  float drop = ((const float*)sel)[2];
  __shared__ unsigned long long carry[3][1024];
  for (int i = tid; i < 3 * 1024; i += 256) ((unsigned long long*)carry)[i] = 0ull;
  __syncthreads();

  bool ghop = (w == 0 && wg > 0);                // consumes across a WG boundary (global)
  bool lhop = (w > 0);                           // consumes within WG (LDS)

  float r[4];
  #pragma unroll
  for (int u = 0; u < 4; u++) r[u] = 0.f;        // B_0 = 0 everywhere
  float rlast = 0.f;
  float pbfill = 0.f;
  int jj[4];
  #pragma unroll
  for (int u = 0; u < 4; u++) jj[u] = col0 + 1 + u;

  const float* zrow = sim + col0;
  // A-store base (tiled 16x128)
  unsigned short* abase = A + (size_t)(col0 >> 7) * 2048 + (col0 & 127);

  float b0[4], b1[4], b2[4], b3[4];
  *(float4*)&b0[0] = *(const float4*)(zrow);
  *(float4*)&b1[0] = *(const float4*)(zrow + 8192);
  *(float4*)&b2[0] = *(const float4*)(zrow + 16384);
  *(float4*)&b3[0] = *(const float4*)(zrow + 24576);

  // carry prefetch: LDS depth-1 (pend), global depth-4 (pq0..pq3 bound to unroll slots)
  const unsigned long long* gsrc = carryG + (size_t)(wg - 1) * 1024;
  unsigned long long pend = 0ull, pq0 = 0ull, pq1 = 0ull, pq2 = 0ull, pq3 = 0ull;
  if (lhop) pend = __hip_atomic_load(&carry[w - 1][0], __ATOMIC_RELAXED, __HIP_MEMORY_SCOPE_WORKGROUP);
  if (ghop) {
    pq0 = __hip_atomic_load(gsrc + 0, __ATOMIC_RELAXED, __HIP_MEMORY_SCOPE_AGENT);
    pq1 = __hip_atomic_load(gsrc + 1, __ATOMIC_RELAXED, __HIP_MEMORY_SCOPE_AGENT);
    pq2 = __hip_atomic_load(gsrc + 2, __ATOMIC_RELAXED, __HIP_MEMORY_SCOPE_AGENT);
    pq3 = __hip_atomic_load(gsrc + 3, __ATOMIC_RELAXED, __HIP_MEMORY_SCOPE_AGENT);
  }

  auto body = [&](float (&dc)[4], unsigned long long& pq, int zi0) {
    unsigned want = (unsigned)(zi0 + 1) << 14;

    float fill = (W == 0) ? ((zi0 == 0) ? 0.f : INFV) : pbfill;
    float pb0 = wave_shr1(rlast, fill, lane);
    // tv[u] = (drop - sim) + B_prev  : identical ops/order to reference zx + prev
    float tv[4];
    { float zx0 = drop - dc[0]; tv[0] = zx0 + pb0; }
    #pragma unroll
    for (int u = 1; u < 4; u++) { float zxu = drop - dc[u]; tv[u] = zxu + r[u - 1]; }
    // prefetch sim row zi0+4 into the freed buffer
    if (zi0 + 4 < 1024) {
      *(float4*)&dc[0] = *(const float4*)(zrow + (size_t)(zi0 + 4) * 8192);
    }
    // in-thread inclusive prefix-min + latest-tie argmin
    int li[4];
    r[0] = tv[0]; li[0] = jj[0];
    #pragma unroll
    for (int u = 1; u < 4; u++) {
      bool t = (tv[u] <= r[u - 1]);
      r[u] = t ? tv[u] : r[u - 1];
      li[u] = t ? jj[u] : li[u - 1];
    }
    // wave-inclusive (min, latest-argmin) scan of thread totals via DPP
    float v = r[3]; int ix = li[3];
    { float sv = dppf<0x111, 0xf>(INFV, v); int si = dppi<0x111, 0xf>(0, ix); if (sv < v) { v = sv; ix = si; } }
    { float sv = dppf<0x112, 0xf>(INFV, v); int si = dppi<0x112, 0xf>(0, ix); if (sv < v) { v = sv; ix = si; } }
    { float sv = dppf<0x114, 0xf>(INFV, v); int si = dppi<0x114, 0xf>(0, ix); if (sv < v) { v = sv; ix = si; } }
    { float sv = dppf<0x118, 0xf>(INFV, v); int si = dppi<0x118, 0xf>(0, ix); if (sv < v) { v = sv; ix = si; } }
    { float sv = dppf<0x142, 0xa>(INFV, v); int si = dppi<0x142, 0xa>(0, ix); if (sv < v) { v = sv; ix = si; } }
    { float sv = dppf<0x143, 0xc>(INFV, v); int si = dppi<0x143, 0xc>(0, ix); if (sv < v) { v = sv; ix = si; } }
    // exclusive within wave
    float exv = dppf<0x111, 0xf>(INFV, v); int exi = dppi<0x111, 0xf>(0, ix);
    float e15 = dppf<0x142, 0xa>(INFV, v); int i15 = dppi<0x142, 0xa>(0, ix);
    float e31 = dppf<0x143, 0xc>(INFV, v); int i31 = dppi<0x143, 0xc>(0, ix);
    if (lane == 16 || lane == 48) { exv = e15; exi = i15; }
    if (lane == 32) { exv = e31; exi = i31; }

    // receive carry C_{W-1}(zi0): prefetched reg if fresh; sleep-spin fallback
    float cv; int ci;
    if (W > 0) {
      unsigned long long d = lhop ? pend : pq;
      if ((((unsigned)d) & 0xFFFFC000u) != want) {
        int guard = 0;
        if (lhop) {
          do {
            __builtin_amdgcn_s_sleep(1);
            d = __hip_atomic_load(&carry[w - 1][zi0], __ATOMIC_RELAXED, __HIP_MEMORY_SCOPE_WORKGROUP);
          } while ((((unsigned)d) & 0xFFFFC000u) != want && ++guard < (1 << 20));
        } else {
          do {
            __builtin_amdgcn_s_sleep(1);
            d = __hip_atomic_load(gsrc + zi0, __ATOMIC_RELAXED, __HIP_MEMORY_SCOPE_AGENT);
          } while ((((unsigned)d) & 0xFFFFC000u) != want && ++guard < (1 << 20));
        }
      }
      cv = __uint_as_float((unsigned)(d >> 32));
      ci = (int)((unsigned)d & 0x3FFFu);
    } else {
      cv = INFV; ci = 0;
    }
    // re-arm prefetch: LDS next row; global 4 rows ahead (covers cross-XCD transport)
    if (lhop && zi0 + 1 < 1024) pend = __hip_atomic_load(&carry[w - 1][zi0 + 1], __ATOMIC_RELAXED, __HIP_MEMORY_SCOPE_WORKGROUP);
    if (ghop && zi0 + 4 < 1024) pq = __hip_atomic_load(gsrc + zi0 + 4, __ATOMIC_RELAXED, __HIP_MEMORY_SCOPE_AGENT);

    // publish combined C_W(zi0) = combine(C_{W-1}, T_W); own cols later -> win ties
    if (lane == 63 && W < 31) {
      bool t = (v <= cv);
      float cov = t ? v : cv;
      int coi = t ? ix : ci;
      unsigned long long pd = ((unsigned long long)__float_as_uint(cov) << 32)
                            | (unsigned)(coi & 0x3FFF) | (unsigned long long)want;
      if (w < 3) __hip_atomic_store(&carry[w][zi0], pd, __ATOMIC_RELAXED, __HIP_MEMORY_SCOPE_WORKGROUP);
      else       __hip_atomic_store(&carryG[(size_t)wg * 1024 + zi0], pd, __ATOMIC_RELAXED, __HIP_MEMORY_SCOPE_AGENT);
    }

    // init = combine(received carry, wave-exclusive); then PARALLEL per-column merge
    float pv; int pi;
    { bool t = (exv <= cv); pv = t ? exv : cv; pi = t ? exi : ci; }
    #pragma unroll
    for (int u = 0; u < 4; u++) {
      bool t = (r[u] <= pv);
      r[u] = t ? r[u] : pv;
      li[u] = t ? li[u] : pi;
    }
    rlast = r[3];
    pbfill = cv;

    unsigned pk0 = (unsigned)li[0] | ((unsigned)li[1] << 16);
    unsigned pk1 = (unsigned)li[2] | ((unsigned)li[3] << 16);
    *(uint2*)(abase + (size_t)(zi0 >> 4) * (64 * 2048) + ((zi0 & 15) << 7)) = make_uint2(pk0, pk1);
  };

  for (int zz = 0; zz < 1024; zz += 4) {
    body(b0, pq0, zz);
    body(b1, pq1, zz + 1);
    body(b2, pq2, zz + 2);
    body(b3, pq3, zz + 3);
  }
  if (wg == 7 && tid == 255) out[2048] = rlast;   // min(D0f[K,N], D1f[K,N])
}

// ---------------- backtrack (tiled A) ----------------
__global__ void btk(const unsigned short* __restrict__ A, float* __restrict__ out) {
  if (threadIdx.x != 0) return;
  int j = 8192;
  for (int zi = 1023; zi >= 0; zi--) {
    int col = j - 1;
    size_t idx = ((size_t)((zi >> 4) * 64 + (col >> 7))) * 2048 + ((zi & 15) << 7) + (col & 127);
    int p = A[idx];
    out[zi] = (float)(p - 1);
    j = p - 1;
  }
}

extern "C" void kernel_launch(void* const* d_in, const int* in_sizes, int n_in,
                              void* d_out, int out_size, void* d_ws, size_t ws_size,
                              hipStream_t stream) {
  (void)in_sizes; (void)n_in; (void)out_size; (void)ws_size;
  const float* T = (const float*)d_in[0];
  const float* E = (const float*)d_in[1];
  char* ws = (char*)d_ws;
  float* sim = (float*)(ws + SIM_OFF);
  unsigned short* A = (unsigned short*)(ws + A_OFF);
  float* invt = (float*)(ws + INVT_OFF);
  float* inve = (float*)(ws + INVE_OFF);
  unsigned* h1 = (unsigned*)(ws + H1_OFF);
  unsigned* h2 = (unsigned*)(ws + H2_OFF);
  unsigned* h3 = (unsigned*)(ws + H3_OFF);
  unsigned* sel = (unsigned*)(ws + SEL_OFF);
  unsigned long long* carryG = (unsigned long long*)(ws + INVT_OFF);  // invt/inve/h1 dead by dpk
  float* out = (float*)d_out;

  hipMemsetAsync(ws + H1_OFF, 0, 16384 + 16384 + 1024 + 64, stream);
  normk<<<9216, 256, 0, stream>>>(T, E, invt, inve, out);
  gemmk<<<dim3(64, 8), 256, 0, stream>>>(T, E, invt, inve, sim);
  histk<<<2048, 256, 0, stream>>>(sim, h1, sel, 0);
  scank<<<1, 256, 0, stream>>>(h1, sel, 0);
  histk<<<2048, 256, 0, stream>>>(sim, h2, sel, 1);
  scank<<<1, 256, 0, stream>>>(h2, sel, 1);
  histk<<<2048, 256, 0, stream>>>(sim, h3, sel, 2);
  scank<<<1, 256, 0, stream>>>(h3, sel, 2);
  hipMemsetAsync(ws + INVT_OFF, 0, 7 * 1024 * 8, stream);   // zero carryG (invt/inve/h1 dead)
  dpk<<<8, 256, 0, stream>>>(sim, sel, carryG, A, out);
  btk<<<1, 64, 0, stream>>>(A, out);
}

// Round 13
// 1159.392 us; speedup vs baseline: 1.0419x; 1.0294x over previous
//
#include <hip/hip_runtime.h>
#include <stdint.h>

#define INFV 1e9f

// ---------------- ws layout (bytes) ----------------
#define SIM_OFF  0           // 1024x8192 f32 sim (never overwritten; zx fused into dpk)
#define A_OFF    33554432    // 1024x8192 u16 prefix-argmin table, tiled 16x128 (4KB tiles)
#define INVT_OFF 50331648    // 1024 f32 (dead after gemmk -> reused as carryG[7][1024] u64)
#define INVE_OFF 50335744    // 8192 f32 (dead after gemmk -> carryG tail)
#define H1_OFF   50368512    // 4096 u32 (dead after scank0 -> carryG tail)
#define H2_OFF   50384896    // 4096 u32 (partially carryG tail; dead after scank1)
#define H3_OFF   50401280    // 256 u32
#define SEL_OFF  50402304    // 16 u32: [0]=rank R, [1]=key prefix, [2]=dropline f32 bits

// ---------------- norms + arange ----------------
__global__ __launch_bounds__(256) void normk(const float* __restrict__ T, const float* __restrict__ E,
                                             float* __restrict__ invt, float* __restrict__ inve,
                                             float* __restrict__ out) {
  int row = blockIdx.x;
  const float* src = (row < 1024) ? (T + (size_t)row * 1024) : (E + (size_t)(row - 1024) * 1024);
  int tid = threadIdx.x;
  float4 v = ((const float4*)src)[tid];
  float s = v.x * v.x + v.y * v.y + v.z * v.z + v.w * v.w;
  #pragma unroll
  for (int d = 1; d < 64; d <<= 1) s += __shfl_xor(s, d);
  __shared__ float wsum[4];
  if ((tid & 63) == 0) wsum[tid >> 6] = s;
  __syncthreads();
  if (tid == 0) {
    float tot = wsum[0] + wsum[1] + wsum[2] + wsum[3];
    float inv = 1.0f / fmaxf(sqrtf(tot), 1e-12f);
    if (row < 1024) invt[row] = inv; else inve[row - 1024] = inv;
  }
  if (blockIdx.x < 4) {
    int i = blockIdx.x * 256 + tid;
    out[1024 + i] = (float)i;
  }
}

// ---------------- f32 GEMM: sim = (T . E^T) * invt * inve ----------------
#define AP 132
__global__ __launch_bounds__(256) void gemmk(const float* __restrict__ T, const float* __restrict__ E,
                                             const float* __restrict__ invt, const float* __restrict__ inve,
                                             float* __restrict__ sim) {
  __shared__ float As[16 * AP];
  __shared__ float Bs[16 * AP];
  int tid = threadIdx.x;
  int i0 = blockIdx.y * 128;
  int j0 = blockIdx.x * 128;
  int tx = tid & 15, ty = tid >> 4;
  float acc[8][8];
  #pragma unroll
  for (int a = 0; a < 8; a++)
    #pragma unroll
    for (int b = 0; b < 8; b++) acc[a][b] = 0.f;

  int q = tid * 2;
  int r = q >> 2;
  int s4 = (q & 3) * 4;
  const float* Ag = T + (size_t)(i0 + r) * 1024 + s4;
  const float* Bg = E + (size_t)(j0 + r) * 1024 + s4;

  for (int kb = 0; kb < 64; kb++) {
    float4 a0 = *(const float4*)(Ag + kb * 16);
    float4 a1 = *(const float4*)(Ag + kb * 16 + 4);
    float4 b0 = *(const float4*)(Bg + kb * 16);
    float4 b1 = *(const float4*)(Bg + kb * 16 + 4);
    __syncthreads();
    As[(s4 + 0) * AP + r] = a0.x; As[(s4 + 1) * AP + r] = a0.y;
    As[(s4 + 2) * AP + r] = a0.z; As[(s4 + 3) * AP + r] = a0.w;
    As[(s4 + 4) * AP + r] = a1.x; As[(s4 + 5) * AP + r] = a1.y;
    As[(s4 + 6) * AP + r] = a1.z; As[(s4 + 7) * AP + r] = a1.w;
    Bs[(s4 + 0) * AP + r] = b0.x; Bs[(s4 + 1) * AP + r] = b0.y;
    Bs[(s4 + 2) * AP + r] = b0.z; Bs[(s4 + 3) * AP + r] = b0.w;
    Bs[(s4 + 4) * AP + r] = b1.x; Bs[(s4 + 5) * AP + r] = b1.y;
    Bs[(s4 + 6) * AP + r] = b1.z; Bs[(s4 + 7) * AP + r] = b1.w;
    __syncthreads();
    #pragma unroll
    for (int k = 0; k < 16; k++) {
      float a[8], b[8];
      *(float4*)&a[0] = *(float4*)&As[k * AP + ty * 8];
      *(float4*)&a[4] = *(float4*)&As[k * AP + ty * 8 + 4];
      *(float4*)&b[0] = *(float4*)&Bs[k * AP + tx * 8];
      *(float4*)&b[4] = *(float4*)&Bs[k * AP + tx * 8 + 4];
      #pragma unroll
      for (int ii = 0; ii < 8; ii++)
        #pragma unroll
        for (int jj = 0; jj < 8; jj++) acc[ii][jj] += a[ii] * b[jj];
    }
  }
  float ie[8];
  #pragma unroll
  for (int jj = 0; jj < 8; jj++) ie[jj] = inve[j0 + tx * 8 + jj];
  #pragma unroll
  for (int ii = 0; ii < 8; ii++) {
    float itv = invt[i0 + ty * 8 + ii];
    float o[8];
    #pragma unroll
    for (int jj = 0; jj < 8; jj++) o[jj] = acc[ii][jj] * itv * ie[jj];
    float* dst = &sim[(size_t)(i0 + ty * 8 + ii) * 8192 + j0 + tx * 8];
    *(float4*)dst = *(float4*)&o[0];
    *(float4*)(dst + 4) = *(float4*)&o[4];
  }
}

// ---------------- exact k-th largest: 3-pass radix select ----------------
__device__ inline unsigned keyOf(float f) {
  unsigned u = __float_as_uint(f);
  return (u & 0x80000000u) ? ~u : (u | 0x80000000u);
}

__global__ __launch_bounds__(256) void histk(const float* __restrict__ sim, unsigned* __restrict__ hist,
                                             const unsigned* __restrict__ sel, int pass) {
  __shared__ unsigned lh[4096];
  int tid = threadIdx.x;
  int nb = (pass == 2) ? 256 : 4096;
  for (int b = tid; b < nb; b += 256) lh[b] = 0;
  __syncthreads();
  unsigned prefix = (pass == 0) ? 0u : sel[1];
  size_t base = (size_t)blockIdx.x * 4096 + tid * 4;
  #pragma unroll
  for (int it = 0; it < 4; it++) {
    float4 f = *(const float4*)(sim + base + it * 1024);
    float vals[4] = {f.x, f.y, f.z, f.w};
    #pragma unroll
    for (int e = 0; e < 4; e++) {
      unsigned u = keyOf(vals[e]);
      if (pass == 0) {
        atomicAdd(&lh[u >> 20], 1u);
      } else if (pass == 1) {
        if ((u >> 20) == (prefix >> 20)) atomicAdd(&lh[(u >> 8) & 0xFFFu], 1u);
      } else {
        if ((u >> 8) == (prefix >> 8)) atomicAdd(&lh[u & 0xFFu], 1u);
      }
    }
  }
  __syncthreads();
  for (int b = tid; b < nb; b += 256) if (lh[b]) atomicAdd(&hist[b], lh[b]);
}

__global__ __launch_bounds__(256) void scank(const unsigned* __restrict__ hist, unsigned* __restrict__ sel, int pass) {
  int tid = threadIdx.x;
  int nb = (pass == 2) ? 256 : 4096;
  int per = nb / 256;
  unsigned R = (pass == 0) ? 5872027u : sel[0];
  unsigned prefix = (pass == 0) ? 0u : sel[1];
  unsigned cnt[16];
  unsigned s = 0;
  for (int i = 0; i < per; i++) { cnt[i] = hist[tid * per + i]; s += cnt[i]; }
  unsigned incl = s;
  #pragma unroll
  for (int d = 1; d < 64; d <<= 1) { unsigned o = __shfl_up(incl, d); if ((tid & 63) >= d) incl += o; }
  __shared__ unsigned wt[4], wsc[4];
  if ((tid & 63) == 63) wt[tid >> 6] = incl;
  __syncthreads();
  if (tid < 4) {
    unsigned v = wt[tid];
    #pragma unroll
    for (int d = 1; d < 4; d <<= 1) { unsigned o = __shfl_up(v, d); if (tid >= d) v += o; }
    wsc[tid] = v;
  }
  __syncthreads();
  unsigned excl = incl - s + ((tid >> 6) ? wsc[(tid >> 6) - 1] : 0u);
  unsigned c = excl;
  for (int i = 0; i < per; i++) {
    unsigned nc = c + cnt[i];
    if (c < R && R <= nc) {
      unsigned bin = (unsigned)(tid * per + i);
      sel[0] = R - c;
      unsigned np_;
      if (pass == 0) np_ = bin << 20;
      else if (pass == 1) np_ = prefix | (bin << 8);
      else np_ = prefix | bin;
      sel[1] = np_;
      if (pass == 2) {
        unsigned key = np_;
        unsigned u = (key & 0x80000000u) ? (key ^ 0x80000000u) : ~key;
        ((float*)sel)[2] = __uint_as_float(u);
      }
    }
    c = nc;
  }
}

// ---------------- DPP helpers ----------------
template<int CTRL, int RM>
__device__ __forceinline__ float dppf(float old, float src) {
  return __int_as_float(__builtin_amdgcn_update_dpp(__float_as_int(old), __float_as_int(src), CTRL, RM, 0xf, false));
}
template<int CTRL, int RM>
__device__ __forceinline__ int dppi(int old, int src) {
  return __builtin_amdgcn_update_dpp(old, src, CTRL, RM, 0xf, false);
}

// full-wave shift-down-by-1 of x (lane l gets lane l-1's x; lane 0 gets `fill`)
__device__ __forceinline__ float wave_shr1(float x, float fill, int lane) {
  float rs  = dppf<0x111, 0xf>(INFV, x);   // row_shr:1 (invalid at lanes 0,16,32,48)
  float r15 = dppf<0x142, 0xa>(INFV, x);   // row_bcast:15 -> lanes 16..31 get l15, 48..63 get l47
  float r31 = dppf<0x143, 0xc>(INFV, x);   // row_bcast:31 -> lanes 32..63 get l31
  float r = rs;
  if (lane == 16 || lane == 48) r = r15;
  if (lane == 32) r = r31;
  if (lane == 0) r = fill;
  return r;
}

// ---------------- Drop-DTW DP: 8-WG x 4-wave pipeline, carry-consume-first body ----------------
// B_zi[j] = prefix-min_j of tv[j] = (drop - sim[zi-1][j-1]) + B_{zi-1}[j-1]   (zx fused).
// A[zi-1][j-1] = latest prefix-argmin <= j (exact backtrack choice of the reference).
// Global wave W = wg*4+w owns cols [1024*wg + 256*w, +256) (4/thread); 32 waves on 32 SIMDs.
// Chained carry C_W(zi): LDS within WG, agent-scope global across the 7 WG boundaries
// (depth-4 register prefetch). BODY ORDER: consume carry FIRST (before this row's sim
// prefetch / A-store are issued) so the prefetched-carry tag check needs only a counted
// vmcnt over statically-known younger ops -- not a vmcnt(0) that drains the ~900cy sim
// load every row (R10-R12's pinned 1460cy period). Protocol/ties verbatim -> bit-exact.
__global__ __launch_bounds__(256) void dpk(const float* __restrict__ sim,
                                           const unsigned* __restrict__ sel,
                                           unsigned long long* __restrict__ carryG,
                                           unsigned short* __restrict__ A, float* __restrict__ out) {
  int tid = threadIdx.x;
  int lane = tid & 63, w = tid >> 6;
  int wg = blockIdx.x;
  int W = wg * 4 + w;
  int col0 = wg * 1024 + tid * 4;                // first of this thread's 4 columns
  float drop = ((const float*)sel)[2];
  __shared__ unsigned long long carry[3][1024];
  for (int i = tid; i < 3 * 1024; i += 256) ((unsigned long long*)carry)[i] = 0ull;
  __syncthreads();

  bool ghop = (w == 0 && wg > 0);                // consumes across a WG boundary (global)
  bool lhop = (w > 0);                           // consumes within WG (LDS)

  float r[4];
  #pragma unroll
  for (int u = 0; u < 4; u++) r[u] = 0.f;        // B_0 = 0 everywhere
  float rlast = 0.f;
  float pbfill = 0.f;
  int jj[4];
  #pragma unroll
  for (int u = 0; u < 4; u++) jj[u] = col0 + 1 + u;

  const float* zrow = sim + col0;
  // A-store base (tiled 16x128)
  unsigned short* abase = A + (size_t)(col0 >> 7) * 2048 + (col0 & 127);

  float b0[4], b1[4], b2[4], b3[4];
  *(float4*)&b0[0] = *(const float4*)(zrow);
  *(float4*)&b1[0] = *(const float4*)(zrow + 8192);
  *(float4*)&b2[0] = *(const float4*)(zrow + 16384);
  *(float4*)&b3[0] = *(const float4*)(zrow + 24576);

  // carry prefetch: LDS depth-1 (pend), global depth-4 (pq0..pq3 bound to unroll slots)
  const unsigned long long* gsrc = carryG + (size_t)(wg - 1) * 1024;
  unsigned long long pend = 0ull, pq0 = 0ull, pq1 = 0ull, pq2 = 0ull, pq3 = 0ull;
  if (lhop) pend = __hip_atomic_load(&carry[w - 1][0], __ATOMIC_RELAXED, __HIP_MEMORY_SCOPE_WORKGROUP);
  if (ghop) {
    pq0 = __hip_atomic_load(gsrc + 0, __ATOMIC_RELAXED, __HIP_MEMORY_SCOPE_AGENT);
    pq1 = __hip_atomic_load(gsrc + 1, __ATOMIC_RELAXED, __HIP_MEMORY_SCOPE_AGENT);
    pq2 = __hip_atomic_load(gsrc + 2, __ATOMIC_RELAXED, __HIP_MEMORY_SCOPE_AGENT);
    pq3 = __hip_atomic_load(gsrc + 3, __ATOMIC_RELAXED, __HIP_MEMORY_SCOPE_AGENT);
  }

  auto body = [&](float (&dc)[4], unsigned long long& pq, int zi0) {
    unsigned want = (unsigned)(zi0 + 1) << 14;

    // 1. consume carry C_{W-1}(zi0) FIRST -- before issuing this row's sim load/A-store.
    float cv; int ci;
    if (W > 0) {
      unsigned long long d = lhop ? pend : pq;
      if (__builtin_expect((((unsigned)d) & 0xFFFFC000u) != want, 0)) {
        int guard = 0;
        if (lhop) {
          do {
            __builtin_amdgcn_s_sleep(1);
            d = __hip_atomic_load(&carry[w - 1][zi0], __ATOMIC_RELAXED, __HIP_MEMORY_SCOPE_WORKGROUP);
          } while ((((unsigned)d) & 0xFFFFC000u) != want && ++guard < (1 << 20));
        } else {
          do {
            __builtin_amdgcn_s_sleep(1);
            d = __hip_atomic_load(gsrc + zi0, __ATOMIC_RELAXED, __HIP_MEMORY_SCOPE_AGENT);
          } while ((((unsigned)d) & 0xFFFFC000u) != want && ++guard < (1 << 20));
        }
      }
      cv = __uint_as_float((unsigned)(d >> 32));
      ci = (int)((unsigned)d & 0x3FFFu);
    } else {
      cv = INFV; ci = 0;
    }
    // 2. re-arm carry prefetch immediately (max slack before next use)
    if (lhop && zi0 + 1 < 1024) pend = __hip_atomic_load(&carry[w - 1][zi0 + 1], __ATOMIC_RELAXED, __HIP_MEMORY_SCOPE_WORKGROUP);
    if (ghop && zi0 + 4 < 1024) pq = __hip_atomic_load(gsrc + zi0 + 4, __ATOMIC_RELAXED, __HIP_MEMORY_SCOPE_AGENT);

    // 3. row compute: tv = (drop - sim) + B_prev  (identical ops/order to reference)
    float fill = (W == 0) ? ((zi0 == 0) ? 0.f : INFV) : pbfill;
    float pb0 = wave_shr1(rlast, fill, lane);
    float tv[4];
    { float zx0 = drop - dc[0]; tv[0] = zx0 + pb0; }
    #pragma unroll
    for (int u = 1; u < 4; u++) { float zxu = drop - dc[u]; tv[u] = zxu + r[u - 1]; }
    // 4. sim prefetch re-arm (younger than the carry use -> never awaited by it)
    if (zi0 + 4 < 1024) {
      *(float4*)&dc[0] = *(const float4*)(zrow + (size_t)(zi0 + 4) * 8192);
    }
    // 5. in-thread inclusive prefix-min + latest-tie argmin
    int li[4];
    r[0] = tv[0]; li[0] = jj[0];
    #pragma unroll
    for (int u = 1; u < 4; u++) {
      bool t = (tv[u] <= r[u - 1]);
      r[u] = t ? tv[u] : r[u - 1];
      li[u] = t ? jj[u] : li[u - 1];
    }
    // wave-inclusive (min, latest-argmin) scan of thread totals via DPP
    float v = r[3]; int ix = li[3];
    { float sv = dppf<0x111, 0xf>(INFV, v); int si = dppi<0x111, 0xf>(0, ix); if (sv < v) { v = sv; ix = si; } }
    { float sv = dppf<0x112, 0xf>(INFV, v); int si = dppi<0x112, 0xf>(0, ix); if (sv < v) { v = sv; ix = si; } }
    { float sv = dppf<0x114, 0xf>(INFV, v); int si = dppi<0x114, 0xf>(0, ix); if (sv < v) { v = sv; ix = si; } }
    { float sv = dppf<0x118, 0xf>(INFV, v); int si = dppi<0x118, 0xf>(0, ix); if (sv < v) { v = sv; ix = si; } }
    { float sv = dppf<0x142, 0xa>(INFV, v); int si = dppi<0x142, 0xa>(0, ix); if (sv < v) { v = sv; ix = si; } }
    { float sv = dppf<0x143, 0xc>(INFV, v); int si = dppi<0x143, 0xc>(0, ix); if (sv < v) { v = sv; ix = si; } }
    // exclusive within wave
    float exv = dppf<0x111, 0xf>(INFV, v); int exi = dppi<0x111, 0xf>(0, ix);
    float e15 = dppf<0x142, 0xa>(INFV, v); int i15 = dppi<0x142, 0xa>(0, ix);
    float e31 = dppf<0x143, 0xc>(INFV, v); int i31 = dppi<0x143, 0xc>(0, ix);
    if (lane == 16 || lane == 48) { exv = e15; exi = i15; }
    if (lane == 32) { exv = e31; exi = i31; }

    // 6. publish combined C_W(zi0) = combine(C_{W-1}, T_W); own cols later -> win ties
    if (lane == 63 && W < 31) {
      bool t = (v <= cv);
      float cov = t ? v : cv;
      int coi = t ? ix : ci;
      unsigned long long pd = ((unsigned long long)__float_as_uint(cov) << 32)
                            | (unsigned)(coi & 0x3FFF) | (unsigned long long)want;
      if (w < 3) __hip_atomic_store(&carry[w][zi0], pd, __ATOMIC_RELAXED, __HIP_MEMORY_SCOPE_WORKGROUP);
      else       __hip_atomic_store(&carryG[(size_t)wg * 1024 + zi0], pd, __ATOMIC_RELAXED, __HIP_MEMORY_SCOPE_AGENT);
    }

    // 7. init = combine(received carry, wave-exclusive); PARALLEL per-column merge; A-store
    float pv; int pi;
    { bool t = (exv <= cv); pv = t ? exv : cv; pi = t ? exi : ci; }
    #pragma unroll
    for (int u = 0; u < 4; u++) {
      bool t = (r[u] <= pv);
      r[u] = t ? r[u] : pv;
      li[u] = t ? li[u] : pi;
    }
    rlast = r[3];
    pbfill = cv;

    unsigned pk0 = (unsigned)li[0] | ((unsigned)li[1] << 16);
    unsigned pk1 = (unsigned)li[2] | ((unsigned)li[3] << 16);
    *(uint2*)(abase + (size_t)(zi0 >> 4) * (64 * 2048) + ((zi0 & 15) << 7)) = make_uint2(pk0, pk1);
  };

  for (int zz = 0; zz < 1024; zz += 4) {
    body(b0, pq0, zz);
    body(b1, pq1, zz + 1);
    body(b2, pq2, zz + 2);
    body(b3, pq3, zz + 3);
  }
  if (wg == 7 && tid == 255) out[2048] = rlast;   // min(D0f[K,N], D1f[K,N])
}

// ---------------- backtrack (tiled A) ----------------
__global__ void btk(const unsigned short* __restrict__ A, float* __restrict__ out) {
  if (threadIdx.x != 0) return;
  int j = 8192;
  for (int zi = 1023; zi >= 0; zi--) {
    int col = j - 1;
    size_t idx = ((size_t)((zi >> 4) * 64 + (col >> 7))) * 2048 + ((zi & 15) << 7) + (col & 127);
    int p = A[idx];
    out[zi] = (float)(p - 1);
    j = p - 1;
  }
}

extern "C" void kernel_launch(void* const* d_in, const int* in_sizes, int n_in,
                              void* d_out, int out_size, void* d_ws, size_t ws_size,
                              hipStream_t stream) {
  (void)in_sizes; (void)n_in; (void)out_size; (void)ws_size;
  const float* T = (const float*)d_in[0];
  const float* E = (const float*)d_in[1];
  char* ws = (char*)d_ws;
  float* sim = (float*)(ws + SIM_OFF);
  unsigned short* A = (unsigned short*)(ws + A_OFF);
  float* invt = (float*)(ws + INVT_OFF);
  float* inve = (float*)(ws + INVE_OFF);
  unsigned* h1 = (unsigned*)(ws + H1_OFF);
  unsigned* h2 = (unsigned*)(ws + H2_OFF);
  unsigned* h3 = (unsigned*)(ws + H3_OFF);
  unsigned* sel = (unsigned*)(ws + SEL_OFF);
  unsigned long long* carryG = (unsigned long long*)(ws + INVT_OFF);  // invt/inve/h1 dead by dpk
  float* out = (float*)d_out;

  hipMemsetAsync(ws + H1_OFF, 0, 16384 + 16384 + 1024 + 64, stream);
  normk<<<9216, 256, 0, stream>>>(T, E, invt, inve, out);
  gemmk<<<dim3(64, 8), 256, 0, stream>>>(T, E, invt, inve, sim);
  histk<<<2048, 256, 0, stream>>>(sim, h1, sel, 0);
  scank<<<1, 256, 0, stream>>>(h1, sel, 0);
  histk<<<2048, 256, 0, stream>>>(sim, h2, sel, 1);
  scank<<<1, 256, 0, stream>>>(h2, sel, 1);
  histk<<<2048, 256, 0, stream>>>(sim, h3, sel, 2);
  scank<<<1, 256, 0, stream>>>(h3, sel, 2);
  hipMemsetAsync(ws + INVT_OFF, 0, 7 * 1024 * 8, stream);   // zero carryG (invt/inve/h1 dead)
  dpk<<<8, 256, 0, stream>>>(sim, sel, carryG, A, out);
  btk<<<1, 64, 0, stream>>>(A, out);
}